// Round 6
// baseline (799.554 us; speedup 1.0000x reference)
//
#include <hip/hip_runtime.h>
#include <math.h>

#define DMODEL 768
#define NHEAD 12
#define DKDIM 64
#define BB 2
#define SS 2048
#define MROWS (BB * SS)   // 4096

typedef unsigned short bf16_t;

// ---- vector loads/stores ----------------------------------------------------
__device__ __forceinline__ float4 ld4(const float* p) { return *(const float4*)p; }
__device__ __forceinline__ float4 ld4(const bf16_t* p) {
    const ushort4 h = *(const ushort4*)p;
    float4 f;
    f.x = __uint_as_float((unsigned)h.x << 16);
    f.y = __uint_as_float((unsigned)h.y << 16);
    f.z = __uint_as_float((unsigned)h.z << 16);
    f.w = __uint_as_float((unsigned)h.w << 16);
    return f;
}
__device__ __forceinline__ bf16_t f2bf(float f) {   // round-to-nearest-even
    unsigned u = __float_as_uint(f);
    u += 0x7fffu + ((u >> 16) & 1u);
    return (bf16_t)(u >> 16);
}
__device__ __forceinline__ void st4(float* p, float4 v) { *(float4*)p = v; }
__device__ __forceinline__ void st4(bf16_t* p, float4 v) {
    ushort4 h;
    h.x = f2bf(v.x); h.y = f2bf(v.y); h.z = f2bf(v.z); h.w = f2bf(v.w);
    *(ushort4*)p = h;
}

// ---------------------------------------------------------------------------
// C[M,N] = A[M,K] @ W[N,K]^T + bias[N]  (torch Linear: x @ W.T + b)
// W/bias are fp32 (raw inputs). A dtype / C dtype via templates:
//   projections: A=fp32 (d_in),  C=bf16 (ws plane)
//   out-proj:    A=bf16 (Ctx),   C=fp32 (d_out)
// 64x64 tile, TK=16, 256 threads, 4x4 acc/thread, fp32 math.
// grid = (N/64, M/64)
// ---------------------------------------------------------------------------
template<typename TA, typename TO>
__global__ __launch_bounds__(256) void gemm_nt(
    const TA* __restrict__ A, const float* __restrict__ W,
    const float* __restrict__ bias, TO* __restrict__ C,
    int Kdim, int Ndim)
{
    __shared__ __align__(16) float As[16][68];
    __shared__ __align__(16) float Bs[16][68];

    const int tid  = threadIdx.x;
    const int tx   = tid & 15;
    const int ty   = tid >> 4;
    const int m0   = blockIdx.y * 64;
    const int n0   = blockIdx.x * 64;
    const int lrow = tid >> 2;
    const int lseg = tid & 3;

    float acc[4][4] = {};

    for (int k0 = 0; k0 < Kdim; k0 += 16) {
        const float4 av = ld4(A + (size_t)(m0 + lrow) * Kdim + k0 + lseg * 4);
        const float4 bv = ld4(W + (size_t)(n0 + lrow) * Kdim + k0 + lseg * 4);
        __syncthreads();
        As[lseg * 4 + 0][lrow] = av.x; As[lseg * 4 + 1][lrow] = av.y;
        As[lseg * 4 + 2][lrow] = av.z; As[lseg * 4 + 3][lrow] = av.w;
        Bs[lseg * 4 + 0][lrow] = bv.x; Bs[lseg * 4 + 1][lrow] = bv.y;
        Bs[lseg * 4 + 2][lrow] = bv.z; Bs[lseg * 4 + 3][lrow] = bv.w;
        __syncthreads();

        #pragma unroll
        for (int kk = 0; kk < 16; kk++) {
            const float4 a4 = *(const float4*)&As[kk][ty * 4];
            const float4 b4 = *(const float4*)&Bs[kk][tx * 4];
            const float a[4]  = { a4.x, a4.y, a4.z, a4.w };
            const float bl[4] = { b4.x, b4.y, b4.z, b4.w };
            #pragma unroll
            for (int i = 0; i < 4; i++)
                #pragma unroll
                for (int j = 0; j < 4; j++)
                    acc[i][j] += a[i] * bl[j];
        }
    }

    const float4 bb4 = ld4(bias + n0 + tx * 4);
    #pragma unroll
    for (int i = 0; i < 4; i++) {
        float4 o;
        o.x = acc[i][0] + bb4.x; o.y = acc[i][1] + bb4.y;
        o.z = acc[i][2] + bb4.z; o.w = acc[i][3] + bb4.w;
        st4(C + (size_t)(m0 + ty * 4 + i) * Ndim + n0 + tx * 4, o);
    }
}

// ---------------------------------------------------------------------------
// Fused flash attention, fp32 online softmax. Q/K/V are bf16 planes [B,S,768]
// in workspace; head h = cols h*64..+63. grid = (S/64, H, B). LDS 52.2 KB.
// Full 64x64 tiles staged: 4 float4 per thread.
// ---------------------------------------------------------------------------
__global__ __launch_bounds__(256) void attn_fused(
    const bf16_t* __restrict__ Q, const bf16_t* __restrict__ K,
    const bf16_t* __restrict__ V, const int* __restrict__ mask,
    bf16_t* __restrict__ O)
{
    __shared__ __align__(16) float Qs[64][68];   // [d][q]
    __shared__ __align__(16) float KPs[64][68];  // [d][k] then [k][q]
    __shared__ __align__(16) float Vs[64][68];   // [k][d]

    const int tid  = threadIdx.x;
    const int tx   = tid & 15;
    const int ty   = tid >> 4;
    const int q0   = blockIdx.x * 64;
    const int h    = blockIdx.y;
    const int b    = blockIdx.z;
    const size_t base = ((size_t)b * SS) * DMODEL + (size_t)h * DKDIM;
    const int lrow = tid >> 2;   // 0..63
    const int lq   = tid & 3;    // 0..3

    #pragma unroll
    for (int c = 0; c < 4; c++) {
        const int seg = lq + 4 * c;   // 0..15
        const float4 qv = ld4(Q + base + (size_t)(q0 + lrow) * DMODEL + seg * 4);
        Qs[seg * 4 + 0][lrow] = qv.x; Qs[seg * 4 + 1][lrow] = qv.y;
        Qs[seg * 4 + 2][lrow] = qv.z; Qs[seg * 4 + 3][lrow] = qv.w;
    }

    float m_run[4], l_run[4], o_acc[4][4] = {};
    #pragma unroll
    for (int i = 0; i < 4; i++) { m_run[i] = -3.0e30f; l_run[i] = 0.0f; }

    const int* mbase = mask + (size_t)b * SS * SS;

    for (int k0 = 0; k0 < SS; k0 += 64) {
        float4 kv[4], vv[4];
        #pragma unroll
        for (int c = 0; c < 4; c++) {
            const int seg = lq + 4 * c;
            kv[c] = ld4(K + base + (size_t)(k0 + lrow) * DMODEL + seg * 4);
            vv[c] = ld4(V + base + (size_t)(k0 + lrow) * DMODEL + seg * 4);
        }
        __syncthreads();
        #pragma unroll
        for (int c = 0; c < 4; c++) {
            const int seg = lq + 4 * c;
            KPs[seg * 4 + 0][lrow] = kv[c].x; KPs[seg * 4 + 1][lrow] = kv[c].y;
            KPs[seg * 4 + 2][lrow] = kv[c].z; KPs[seg * 4 + 3][lrow] = kv[c].w;
            *(float4*)&Vs[lrow][seg * 4] = vv[c];
        }
        __syncthreads();

        // S = Q @ K^T
        float s[4][4] = {};
        #pragma unroll 16
        for (int d = 0; d < 64; d++) {
            const float4 a4 = *(const float4*)&Qs[d][ty * 4];
            const float4 b4 = *(const float4*)&KPs[d][tx * 4];
            const float a[4]  = { a4.x, a4.y, a4.z, a4.w };
            const float bl[4] = { b4.x, b4.y, b4.z, b4.w };
            #pragma unroll
            for (int i = 0; i < 4; i++)
                #pragma unroll
                for (int j = 0; j < 4; j++)
                    s[i][j] += a[i] * bl[j];
        }

        // scale + mask + online softmax (row = ty*4+i; 16 tx lanes share a row)
        float p[4][4];
        #pragma unroll
        for (int i = 0; i < 4; i++) {
            const int4 mk = *(const int4*)(mbase + (size_t)(q0 + ty * 4 + i) * SS + k0 + tx * 4);
            s[i][0] = mk.x ? s[i][0] * 0.125f : -1.0e9f;
            s[i][1] = mk.y ? s[i][1] * 0.125f : -1.0e9f;
            s[i][2] = mk.z ? s[i][2] * 0.125f : -1.0e9f;
            s[i][3] = mk.w ? s[i][3] * 0.125f : -1.0e9f;

            float mx = fmaxf(fmaxf(s[i][0], s[i][1]), fmaxf(s[i][2], s[i][3]));
            mx = fmaxf(mx, __shfl_xor(mx, 1, 16));
            mx = fmaxf(mx, __shfl_xor(mx, 2, 16));
            mx = fmaxf(mx, __shfl_xor(mx, 4, 16));
            mx = fmaxf(mx, __shfl_xor(mx, 8, 16));

            const float m_new = fmaxf(m_run[i], mx);
            const float alpha = expf(m_run[i] - m_new);
            p[i][0] = expf(s[i][0] - m_new);
            p[i][1] = expf(s[i][1] - m_new);
            p[i][2] = expf(s[i][2] - m_new);
            p[i][3] = expf(s[i][3] - m_new);

            float rs = p[i][0] + p[i][1] + p[i][2] + p[i][3];
            rs += __shfl_xor(rs, 1, 16);
            rs += __shfl_xor(rs, 2, 16);
            rs += __shfl_xor(rs, 4, 16);
            rs += __shfl_xor(rs, 8, 16);

            l_run[i] = l_run[i] * alpha + rs;
            m_run[i] = m_new;
            o_acc[i][0] *= alpha; o_acc[i][1] *= alpha;
            o_acc[i][2] *= alpha; o_acc[i][3] *= alpha;
        }

        __syncthreads();   // all S-GEMM reads of KPs done before overwrite as P^T
        #pragma unroll
        for (int i = 0; i < 4; i++) {
            KPs[tx * 4 + 0][ty * 4 + i] = p[i][0];
            KPs[tx * 4 + 1][ty * 4 + i] = p[i][1];
            KPs[tx * 4 + 2][ty * 4 + i] = p[i][2];
            KPs[tx * 4 + 3][ty * 4 + i] = p[i][3];
        }
        __syncthreads();

        // O += P @ V
        #pragma unroll 16
        for (int kk = 0; kk < 64; kk++) {
            const float4 p4 = *(const float4*)&KPs[kk][ty * 4];
            const float4 v4 = *(const float4*)&Vs[kk][tx * 4];
            const float a[4]  = { p4.x, p4.y, p4.z, p4.w };
            const float bl[4] = { v4.x, v4.y, v4.z, v4.w };
            #pragma unroll
            for (int i = 0; i < 4; i++)
                #pragma unroll
                for (int j = 0; j < 4; j++)
                    o_acc[i][j] += a[i] * bl[j];
        }
    }

    #pragma unroll
    for (int i = 0; i < 4; i++) {
        const float inv = 1.0f / l_run[i];
        float4 o;
        o.x = o_acc[i][0] * inv; o.y = o_acc[i][1] * inv;
        o.z = o_acc[i][2] * inv; o.w = o_acc[i][3] * inv;
        st4(O + base + (size_t)(q0 + ty * 4 + i) * DMODEL + tx * 4, o);
    }
}

// ---------------------------------------------------------------------------
extern "C" void kernel_launch(void* const* d_in, const int* in_sizes, int n_in,
                              void* d_out, int out_size, void* d_ws, size_t ws_size,
                              hipStream_t stream)
{
    const float* q    = (const float*)d_in[0];
    const float* k    = (const float*)d_in[1];
    const float* v    = (const float*)d_in[2];
    const int*   mask = (const int*)  d_in[3];
    const float* Wq   = (const float*)d_in[4];
    const float* bq   = (const float*)d_in[5];
    const float* Wk   = (const float*)d_in[6];
    const float* bk   = (const float*)d_in[7];
    const float* Wv   = (const float*)d_in[8];
    const float* bv   = (const float*)d_in[9];
    const float* Wo   = (const float*)d_in[10];
    const float* bo   = (const float*)d_in[11];
    float* out = (float*)d_out;   // fp32 output (reference returns float32)

    // ws: 4 bf16 planes [4096 x 768] = 25.2 MB (proven in-bounds in round 5)
    bf16_t* wsb = (bf16_t*)d_ws;
    const size_t plane = (size_t)MROWS * DMODEL;   // 3,145,728 elements
    bf16_t* Qp  = wsb;
    bf16_t* Kp  = wsb + plane;
    bf16_t* Vp  = wsb + 2 * plane;
    bf16_t* Ctx = wsb + 3 * plane;

    const dim3 gb(DMODEL / 64, MROWS / 64);   // (12, 64)
    const dim3 tb(256);

    gemm_nt<float, bf16_t><<<gb, tb, 0, stream>>>(q, Wq, bq, Qp, DMODEL, DMODEL);
    gemm_nt<float, bf16_t><<<gb, tb, 0, stream>>>(k, Wk, bk, Kp, DMODEL, DMODEL);
    gemm_nt<float, bf16_t><<<gb, tb, 0, stream>>>(v, Wv, bv, Vp, DMODEL, DMODEL);

    attn_fused<<<dim3(SS / 64, NHEAD, BB), tb, 0, stream>>>(Qp, Kp, Vp, mask, Ctx);

    gemm_nt<bf16_t, float><<<gb, tb, 0, stream>>>(Ctx, Wo, bo, out, DMODEL, DMODEL);
}

// Round 7
// 477.983 us; speedup vs baseline: 1.6728x; 1.6728x over previous
//
#include <hip/hip_runtime.h>
#include <math.h>

#define DMODEL 768
#define NHEAD 12
#define DKDIM 64
#define BB 2
#define SS 2048
#define MROWS (BB * SS)    // 4096
#define WELEM (DMODEL * DMODEL)  // 589824

typedef unsigned short bf16_t;
typedef __attribute__((ext_vector_type(8))) short s8;   // 8 bf16 = 4 VGPRs (MFMA A/B frag)
typedef __attribute__((ext_vector_type(4))) float f4;   // MFMA C/D frag

#define MFMA(a, b, c) __builtin_amdgcn_mfma_f32_16x16x32_bf16((a), (b), (c), 0, 0, 0)

__device__ __forceinline__ bf16_t f2bf(float f) {   // round-to-nearest-even
    unsigned u = __float_as_uint(f);
    u += 0x7fffu + ((u >> 16) & 1u);
    return (bf16_t)(u >> 16);
}
__device__ __forceinline__ unsigned pack2(float a, float b) {
    return (unsigned)f2bf(a) | ((unsigned)f2bf(b) << 16);
}
// 8 consecutive bf16 -> fragment
__device__ __forceinline__ s8 ldfrag(const bf16_t* p) {
    union { uint4 u; s8 s; } x;
    x.u = *(const uint4*)p;
    return x.s;
}
// 8 consecutive fp32 -> bf16 fragment
__device__ __forceinline__ s8 ldfrag_f(const float* p) {
    const float4 a = *(const float4*)p;
    const float4 b = *(const float4*)(p + 4);
    union { unsigned u[4]; s8 s; } x;
    x.u[0] = pack2(a.x, a.y); x.u[1] = pack2(a.z, a.w);
    x.u[2] = pack2(b.x, b.y); x.u[3] = pack2(b.z, b.w);
    return x.s;
}
// dual-dtype fragment load (overload dispatch at compile time)
__device__ __forceinline__ s8 ldAB(const bf16_t* p) { return ldfrag(p); }
__device__ __forceinline__ s8 ldAB(const float* p)  { return ldfrag_f(p); }

// ---------------------------------------------------------------------------
// Weight prepass: fp32 -> bf16, 4 matrices of 768x768. grid (576, 4), 256 thr.
// ---------------------------------------------------------------------------
__global__ void cvt_weights(const float* __restrict__ W0, const float* __restrict__ W1,
                            const float* __restrict__ W2, const float* __restrict__ W3,
                            bf16_t* __restrict__ dst)
{
    const float* src = (blockIdx.y == 0) ? W0 : (blockIdx.y == 1) ? W1
                     : (blockIdx.y == 2) ? W2 : W3;
    bf16_t* d = dst + (size_t)blockIdx.y * WELEM;
    const int i = (blockIdx.x * 256 + threadIdx.x) * 4;
    const float4 v = *(const float4*)(src + i);
    ushort4 h;
    h.x = f2bf(v.x); h.y = f2bf(v.y); h.z = f2bf(v.z); h.w = f2bf(v.w);
    *(ushort4*)(d + i) = h;
}

// ---------------------------------------------------------------------------
// MFMA GEMM: C[M,N] = A[M,K] @ Wb[N,K]^T + bias[N]
// block 256 = 4 waves; wave w owns rows [m0+16w, +16); 4 n-tiles of 16.
// A/B frags straight from global (K contiguous in both). grid (N/64, M/64).
// ---------------------------------------------------------------------------
template<typename TA, typename TO>
__global__ __launch_bounds__(256) void gemm_mfma(
    const TA* __restrict__ A, const bf16_t* __restrict__ Wb,
    const float* __restrict__ bias, TO* __restrict__ C,
    int Kdim, int Ndim)
{
    const int tid  = threadIdx.x;
    const int lane = tid & 63;
    const int w    = tid >> 6;
    const int l15  = lane & 15;
    const int quad = lane >> 4;
    const int m0   = blockIdx.y * 64;
    const int n0   = blockIdx.x * 64;

    const TA* arow = A + (size_t)(m0 + w * 16 + l15) * Kdim + quad * 8;
    const bf16_t* wrow0 = Wb + (size_t)(n0 +  0 + l15) * Kdim + quad * 8;
    const bf16_t* wrow1 = Wb + (size_t)(n0 + 16 + l15) * Kdim + quad * 8;
    const bf16_t* wrow2 = Wb + (size_t)(n0 + 32 + l15) * Kdim + quad * 8;
    const bf16_t* wrow3 = Wb + (size_t)(n0 + 48 + l15) * Kdim + quad * 8;

    f4 acc0 = {0.f,0.f,0.f,0.f}, acc1 = {0.f,0.f,0.f,0.f};
    f4 acc2 = {0.f,0.f,0.f,0.f}, acc3 = {0.f,0.f,0.f,0.f};

    for (int k = 0; k < Kdim; k += 32) {
        const s8 af = ldAB(arow + k);
        acc0 = MFMA(af, ldfrag(wrow0 + k), acc0);
        acc1 = MFMA(af, ldfrag(wrow1 + k), acc1);
        acc2 = MFMA(af, ldfrag(wrow2 + k), acc2);
        acc3 = MFMA(af, ldfrag(wrow3 + k), acc3);
    }

    // epilogue: C row = m0 + 16w + quad*4 + reg, col = n0 + 16nt + l15
    f4 accs[4] = { acc0, acc1, acc2, acc3 };
    #pragma unroll
    for (int nt = 0; nt < 4; nt++) {
        const float bb = bias[n0 + nt * 16 + l15];
        #pragma unroll
        for (int reg = 0; reg < 4; reg++) {
            const float val = accs[nt][reg] + bb;
            TO* dst = C + (size_t)(m0 + w * 16 + quad * 4 + reg) * Ndim + n0 + nt * 16 + l15;
            if constexpr (sizeof(TO) == 2) *dst = f2bf(val);
            else                           *dst = val;
        }
    }
}

// ---------------------------------------------------------------------------
// MFMA flash attention. Q/K/V bf16 planes [B,S,768], head h = cols 64h..+63.
// Block = (64 Q rows, h, b); 4 waves, wave w owns Q rows [q0+16w, +16).
// S = Q K^T via MFMA (frags direct from global); softmax in C-layout;
// P -> per-wave LDS (A-layout, 2 bf16/word); V -> LDS transposed (B-layout).
// LDS: Vs 9216 B + Ps 9216 B = 18.4 KB. grid (S/64, H, B).
// ---------------------------------------------------------------------------
__global__ __launch_bounds__(256) void attn_mfma(
    const bf16_t* __restrict__ Q, const bf16_t* __restrict__ K,
    const bf16_t* __restrict__ V, const int* __restrict__ mask,
    bf16_t* __restrict__ O)
{
    __shared__ unsigned Vs[64][36];       // Vs[d][kpair]: V[2kp][d] | V[2kp+1][d]<<16
    __shared__ unsigned Ps[4][16][36];    // per-wave P, A-layout packed pairs

    const int tid  = threadIdx.x;
    const int lane = tid & 63;
    const int w    = tid >> 6;
    const int l15  = lane & 15;
    const int quad = lane >> 4;
    const int q0   = blockIdx.x * 64;
    const int h    = blockIdx.y;
    const int b    = blockIdx.z;
    const size_t base = ((size_t)b * SS) * DMODEL + (size_t)h * DKDIM;

    // Q fragments: row q0+16w+l15, d chunks {quad*8, 32+quad*8}
    const bf16_t* qrow = Q + base + (size_t)(q0 + w * 16 + l15) * DMODEL + quad * 8;
    const s8 qf0 = ldfrag(qrow);
    const s8 qf1 = ldfrag(qrow + 32);

    f4 oacc[4];
    float m_run[4], l_run[4];
    #pragma unroll
    for (int i = 0; i < 4; i++) {
        oacc[i] = (f4){0.f, 0.f, 0.f, 0.f};
        m_run[i] = -3.0e30f; l_run[i] = 0.0f;
    }

    // V staging role: k-pair + d-octet
    const int kp  = tid & 31;
    const int oct = tid >> 5;

    const int* mrow = mask + (size_t)b * SS * SS + (size_t)(q0 + w * 16 + quad * 4) * SS;

    for (int k0 = 0; k0 < SS; k0 += 64) {
        // prefetch V rows 2kp, 2kp+1 (d-octet oct)
        const bf16_t* vrow = V + base + (size_t)(k0 + 2 * kp) * DMODEL + oct * 8;
        const uint4 va = *(const uint4*)vrow;
        const uint4 vb = *(const uint4*)(vrow + DMODEL);
        __syncthreads();                     // prev iteration's PV reads done
        {
            const unsigned short* pa = (const unsigned short*)&va;
            const unsigned short* pb = (const unsigned short*)&vb;
            #pragma unroll
            for (int i = 0; i < 8; i++)
                Vs[oct * 8 + i][kp] = (unsigned)pa[i] | ((unsigned)pb[i] << 16);
        }

        // S = Q K^T  (no LDS involved)
        f4 sacc[4];
        #pragma unroll
        for (int nt = 0; nt < 4; nt++) {
            const bf16_t* krow = K + base + (size_t)(k0 + nt * 16 + l15) * DMODEL + quad * 8;
            f4 z = {0.f, 0.f, 0.f, 0.f};
            z = MFMA(qf0, ldfrag(krow), z);
            z = MFMA(qf1, ldfrag(krow + 32), z);
            sacc[nt] = z;
        }

        // mask + online softmax; lane holds S[q=quad*4+reg][k'=l15+16nt]
        float p[4][4];
        #pragma unroll
        for (int reg = 0; reg < 4; reg++) {
            float sv[4];
            #pragma unroll
            for (int nt = 0; nt < 4; nt++) {
                const int mk = mrow[(size_t)reg * SS + k0 + nt * 16 + l15];
                sv[nt] = mk ? sacc[nt][reg] * 0.125f : -1.0e9f;
            }
            float mx = fmaxf(fmaxf(sv[0], sv[1]), fmaxf(sv[2], sv[3]));
            mx = fmaxf(mx, __shfl_xor(mx, 1, 16));
            mx = fmaxf(mx, __shfl_xor(mx, 2, 16));
            mx = fmaxf(mx, __shfl_xor(mx, 4, 16));
            mx = fmaxf(mx, __shfl_xor(mx, 8, 16));

            const float m_new = fmaxf(m_run[reg], mx);
            const float alpha = __expf(m_run[reg] - m_new);
            float rs = 0.f;
            #pragma unroll
            for (int nt = 0; nt < 4; nt++) {
                p[reg][nt] = __expf(sv[nt] - m_new);
                rs += p[reg][nt];
            }
            rs += __shfl_xor(rs, 1, 16);
            rs += __shfl_xor(rs, 2, 16);
            rs += __shfl_xor(rs, 4, 16);
            rs += __shfl_xor(rs, 8, 16);

            l_run[reg] = l_run[reg] * alpha + rs;
            m_run[reg] = m_new;
            #pragma unroll
            for (int dt = 0; dt < 4; dt++) oacc[dt][reg] *= alpha;
        }

        // P (C-layout) -> Ps[w] (A-layout): row=quad*4+reg, col=l15+16nt,
        // pack col pairs via shfl; even lanes write one b32 per (reg,nt).
        #pragma unroll
        for (int reg = 0; reg < 4; reg++) {
            #pragma unroll
            for (int nt = 0; nt < 4; nt++) {
                const float mine  = p[reg][nt];
                const float other = __shfl_xor(mine, 1, 16);
                if ((lane & 1) == 0)
                    Ps[w][quad * 4 + reg][nt * 8 + (l15 >> 1)] = pack2(mine, other);
            }
        }
        __syncthreads();                     // Vs fully staged (all waves)

        // O += P @ V
        #pragma unroll
        for (int kt = 0; kt < 2; kt++) {
            union { uint4 u; s8 s; } pf;
            pf.u = *(const uint4*)&Ps[w][l15][kt * 16 + quad * 4];
            #pragma unroll
            for (int dt = 0; dt < 4; dt++) {
                union { uint4 u; s8 s; } vf;
                vf.u = *(const uint4*)&Vs[dt * 16 + l15][kt * 16 + quad * 4];
                oacc[dt] = MFMA(pf.s, vf.s, oacc[dt]);
            }
        }
    }

    // epilogue: O row = q0+16w+quad*4+reg, col = 16dt+l15 (head-relative)
    #pragma unroll
    for (int reg = 0; reg < 4; reg++) {
        const float inv = 1.0f / l_run[reg];
        #pragma unroll
        for (int dt = 0; dt < 4; dt++) {
            O[base + (size_t)(q0 + w * 16 + quad * 4 + reg) * DMODEL + dt * 16 + l15] =
                f2bf(oacc[dt][reg] * inv);
        }
    }
}

// ---------------------------------------------------------------------------
extern "C" void kernel_launch(void* const* d_in, const int* in_sizes, int n_in,
                              void* d_out, int out_size, void* d_ws, size_t ws_size,
                              hipStream_t stream)
{
    const float* q    = (const float*)d_in[0];
    const float* k    = (const float*)d_in[1];
    const float* v    = (const float*)d_in[2];
    const int*   mask = (const int*)  d_in[3];
    const float* Wq   = (const float*)d_in[4];
    const float* bq   = (const float*)d_in[5];
    const float* Wk   = (const float*)d_in[6];
    const float* bk   = (const float*)d_in[7];
    const float* Wv   = (const float*)d_in[8];
    const float* bv   = (const float*)d_in[9];
    const float* Wo   = (const float*)d_in[10];
    const float* bo   = (const float*)d_in[11];
    float* out = (float*)d_out;

    // ws: 4 bf16 planes [4096x768] (25.2 MB) + 4 bf16 weight mats (4.5 MB)
    bf16_t* wsb = (bf16_t*)d_ws;
    const size_t plane = (size_t)MROWS * DMODEL;   // 3,145,728
    bf16_t* Qp  = wsb;
    bf16_t* Kp  = wsb + plane;
    bf16_t* Vp  = wsb + 2 * plane;
    bf16_t* Ctx = wsb + 3 * plane;
    bf16_t* Wqb = wsb + 4 * plane;
    bf16_t* Wkb = Wqb + WELEM;
    bf16_t* Wvb = Wkb + WELEM;
    bf16_t* Wob = Wvb + WELEM;

    cvt_weights<<<dim3(WELEM / 1024, 4), 256, 0, stream>>>(Wq, Wk, Wv, Wo, Wqb);

    const dim3 gb(DMODEL / 64, MROWS / 64);   // (12, 64)
    const dim3 tb(256);

    gemm_mfma<float, bf16_t><<<gb, tb, 0, stream>>>(q, Wqb, bq, Qp, DMODEL, DMODEL);
    gemm_mfma<float, bf16_t><<<gb, tb, 0, stream>>>(k, Wkb, bk, Kp, DMODEL, DMODEL);
    gemm_mfma<float, bf16_t><<<gb, tb, 0, stream>>>(v, Wvb, bv, Vp, DMODEL, DMODEL);

    attn_mfma<<<dim3(SS / 64, NHEAD, BB), tb, 0, stream>>>(Qp, Kp, Vp, mask, Ctx);

    gemm_mfma<bf16_t, float><<<gb, tb, 0, stream>>>(Ctx, Wob, bo, out, DMODEL, DMODEL);
}

// Round 8
// 340.080 us; speedup vs baseline: 2.3511x; 1.4055x over previous
//
#include <hip/hip_runtime.h>
#include <math.h>

#define DMODEL 768
#define NHEAD 12
#define DKDIM 64
#define BB 2
#define SS 2048
#define MROWS (BB * SS)    // 4096
#define WELEM (DMODEL * DMODEL)  // 589824

typedef unsigned short bf16_t;
typedef __attribute__((ext_vector_type(8))) short s8;   // 8 bf16 = 4 VGPRs (MFMA A/B frag)
typedef __attribute__((ext_vector_type(4))) float f4;   // MFMA C/D frag

#define MFMA(a, b, c) __builtin_amdgcn_mfma_f32_16x16x32_bf16((a), (b), (c), 0, 0, 0)

__device__ __forceinline__ bf16_t f2bf(float f) {   // round-to-nearest-even
    unsigned u = __float_as_uint(f);
    u += 0x7fffu + ((u >> 16) & 1u);
    return (bf16_t)(u >> 16);
}
__device__ __forceinline__ unsigned pack2(float a, float b) {
    return (unsigned)f2bf(a) | ((unsigned)f2bf(b) << 16);
}
__device__ __forceinline__ s8 ldfrag(const bf16_t* p) {
    union { uint4 u; s8 s; } x;
    x.u = *(const uint4*)p;
    return x.s;
}

// stage 16 consecutive elements -> 2 x uint4 of packed bf16
__device__ __forceinline__ void ld_stage(const bf16_t* p, uint4& u0, uint4& u1) {
    u0 = *(const uint4*)p;
    u1 = *(const uint4*)(p + 8);
}
__device__ __forceinline__ void ld_stage(const float* p, uint4& u0, uint4& u1) {
    const float4 f0 = *(const float4*)p;
    const float4 f1 = *(const float4*)(p + 4);
    const float4 f2 = *(const float4*)(p + 8);
    const float4 f3 = *(const float4*)(p + 12);
    u0.x = pack2(f0.x, f0.y); u0.y = pack2(f0.z, f0.w);
    u0.z = pack2(f1.x, f1.y); u0.w = pack2(f1.z, f1.w);
    u1.x = pack2(f2.x, f2.y); u1.y = pack2(f2.z, f2.w);
    u1.z = pack2(f3.x, f3.y); u1.w = pack2(f3.z, f3.w);
}

// ---------------------------------------------------------------------------
// Weight prepass: fp32 -> bf16, 4 matrices of 768x768. grid (576, 4), 256 thr.
// ---------------------------------------------------------------------------
__global__ void cvt_weights(const float* __restrict__ W0, const float* __restrict__ W1,
                            const float* __restrict__ W2, const float* __restrict__ W3,
                            bf16_t* __restrict__ dst)
{
    const float* src = (blockIdx.y == 0) ? W0 : (blockIdx.y == 1) ? W1
                     : (blockIdx.y == 2) ? W2 : W3;
    bf16_t* d = dst + (size_t)blockIdx.y * WELEM;
    const int i = (blockIdx.x * 256 + threadIdx.x) * 4;
    const float4 v = *(const float4*)(src + i);
    ushort4 h;
    h.x = f2bf(v.x); h.y = f2bf(v.y); h.z = f2bf(v.z); h.w = f2bf(v.w);
    *(ushort4*)(d + i) = h;
}

// ---------------------------------------------------------------------------
// LDS-staged MFMA GEMM (m93-style): C[M,768] = A[M,768] @ W[768,768]^T + bias.
// 128x128 block tile, BK=32, 256 thr = 4 waves in 2x2 (each wave 64x64 =
// 4x4 MFMA tiles). LDS: A-tile 8 KB + B-tile 8 KB, 16B-block XOR swizzle
// (blk ^ (row&3)) -> minimum-conflict ds_read_b128/ds_write_b128.
// blockIdx.z selects one of 3 (A,W,bias,C) problem instances (fused QKV).
// grid = (768/128, M/128, nz)
// ---------------------------------------------------------------------------
template<typename TA, typename TO>
__global__ __launch_bounds__(256) void gemm_tiled(
    const TA* __restrict__ A0, const TA* __restrict__ A1, const TA* __restrict__ A2,
    const bf16_t* __restrict__ W0, const bf16_t* __restrict__ W1, const bf16_t* __restrict__ W2,
    const float* __restrict__ bias0, const float* __restrict__ bias1, const float* __restrict__ bias2,
    TO* __restrict__ C0, TO* __restrict__ C1, TO* __restrict__ C2)
{
    __shared__ uint4 As4[128 * 4];   // 128 rows x 4 swizzled 16B blocks (8 KB)
    __shared__ uint4 Bs4[128 * 4];

    const int z = blockIdx.z;
    const TA*     A    = (z == 0) ? A0 : (z == 1) ? A1 : A2;
    const bf16_t* W    = (z == 0) ? W0 : (z == 1) ? W1 : W2;
    const float*  bias = (z == 0) ? bias0 : (z == 1) ? bias1 : bias2;
    TO*           C    = (z == 0) ? C0 : (z == 1) ? C1 : C2;

    const int tid  = threadIdx.x;
    const int lane = tid & 63;
    const int w    = tid >> 6;
    const int wm   = w & 1;
    const int wn   = w >> 1;
    const int l15  = lane & 15;
    const int quad = lane >> 4;
    const int m0   = blockIdx.y * 128;
    const int n0   = blockIdx.x * 128;

    const int srow  = tid >> 1;   // 0..127 staging row
    const int shalf = tid & 1;    // which 16-element k-half
    const int sw    = srow & 3;

    const TA*     aptr = A + (size_t)(m0 + srow) * DMODEL + shalf * 16;
    const bf16_t* wptr = W + (size_t)(n0 + srow) * DMODEL + shalf * 16;

    f4 acc[4][4];
    #pragma unroll
    for (int i = 0; i < 4; i++)
        #pragma unroll
        for (int j = 0; j < 4; j++)
            acc[i][j] = (f4){0.f, 0.f, 0.f, 0.f};

    for (int k0 = 0; k0 < DMODEL; k0 += 32) {
        uint4 au0, au1, bu0, bu1;
        ld_stage(aptr + k0, au0, au1);
        ld_stage(wptr + k0, bu0, bu1);
        __syncthreads();   // previous iteration's fragment reads complete
        As4[srow * 4 + ((shalf * 2 + 0) ^ sw)] = au0;
        As4[srow * 4 + ((shalf * 2 + 1) ^ sw)] = au1;
        Bs4[srow * 4 + ((shalf * 2 + 0) ^ sw)] = bu0;
        Bs4[srow * 4 + ((shalf * 2 + 1) ^ sw)] = bu1;
        __syncthreads();

        s8 af[4], bf[4];
        #pragma unroll
        for (int t = 0; t < 4; t++) {
            const int ar = wm * 64 + t * 16 + l15;
            const int br = wn * 64 + t * 16 + l15;
            union { uint4 u; s8 s; } xa, xb;
            xa.u = As4[ar * 4 + (quad ^ (ar & 3))];
            xb.u = Bs4[br * 4 + (quad ^ (br & 3))];
            af[t] = xa.s;
            bf[t] = xb.s;
        }
        #pragma unroll
        for (int mt = 0; mt < 4; mt++)
            #pragma unroll
            for (int nt = 0; nt < 4; nt++)
                acc[mt][nt] = MFMA(af[mt], bf[nt], acc[mt][nt]);
    }

    // epilogue: row = m0+64wm+16mt+4quad+reg, col = n0+64wn+16nt+l15
    #pragma unroll
    for (int mt = 0; mt < 4; mt++) {
        #pragma unroll
        for (int nt = 0; nt < 4; nt++) {
            const int col = n0 + wn * 64 + nt * 16 + l15;
            const float bb = bias[col];
            #pragma unroll
            for (int reg = 0; reg < 4; reg++) {
                const int row = m0 + wm * 64 + mt * 16 + quad * 4 + reg;
                const float val = acc[mt][nt][reg] + bb;
                TO* dst = C + (size_t)row * DMODEL + col;
                if constexpr (sizeof(TO) == 2) *dst = f2bf(val);
                else                           *dst = val;
            }
        }
    }
}

// ---------------------------------------------------------------------------
// MFMA flash attention (unchanged from round 7 — verified at 177 us).
// ---------------------------------------------------------------------------
__global__ __launch_bounds__(256) void attn_mfma(
    const bf16_t* __restrict__ Q, const bf16_t* __restrict__ K,
    const bf16_t* __restrict__ V, const int* __restrict__ mask,
    bf16_t* __restrict__ O)
{
    __shared__ unsigned Vs[64][36];       // Vs[d][kpair]
    __shared__ unsigned Ps[4][16][36];    // per-wave P, A-layout packed pairs

    const int tid  = threadIdx.x;
    const int lane = tid & 63;
    const int w    = tid >> 6;
    const int l15  = lane & 15;
    const int quad = lane >> 4;
    const int q0   = blockIdx.x * 64;
    const int h    = blockIdx.y;
    const int b    = blockIdx.z;
    const size_t base = ((size_t)b * SS) * DMODEL + (size_t)h * DKDIM;

    const bf16_t* qrow = Q + base + (size_t)(q0 + w * 16 + l15) * DMODEL + quad * 8;
    const s8 qf0 = ldfrag(qrow);
    const s8 qf1 = ldfrag(qrow + 32);

    f4 oacc[4];
    float m_run[4], l_run[4];
    #pragma unroll
    for (int i = 0; i < 4; i++) {
        oacc[i] = (f4){0.f, 0.f, 0.f, 0.f};
        m_run[i] = -3.0e30f; l_run[i] = 0.0f;
    }

    const int kp  = tid & 31;
    const int oct = tid >> 5;

    const int* mrow = mask + (size_t)b * SS * SS + (size_t)(q0 + w * 16 + quad * 4) * SS;

    for (int k0 = 0; k0 < SS; k0 += 64) {
        const bf16_t* vrow = V + base + (size_t)(k0 + 2 * kp) * DMODEL + oct * 8;
        const uint4 va = *(const uint4*)vrow;
        const uint4 vb = *(const uint4*)(vrow + DMODEL);
        __syncthreads();
        {
            const unsigned short* pa = (const unsigned short*)&va;
            const unsigned short* pb = (const unsigned short*)&vb;
            #pragma unroll
            for (int i = 0; i < 8; i++)
                Vs[oct * 8 + i][kp] = (unsigned)pa[i] | ((unsigned)pb[i] << 16);
        }

        f4 sacc[4];
        #pragma unroll
        for (int nt = 0; nt < 4; nt++) {
            const bf16_t* krow = K + base + (size_t)(k0 + nt * 16 + l15) * DMODEL + quad * 8;
            f4 zz = {0.f, 0.f, 0.f, 0.f};
            zz = MFMA(qf0, ldfrag(krow), zz);
            zz = MFMA(qf1, ldfrag(krow + 32), zz);
            sacc[nt] = zz;
        }

        float p[4][4];
        #pragma unroll
        for (int reg = 0; reg < 4; reg++) {
            float sv[4];
            #pragma unroll
            for (int nt = 0; nt < 4; nt++) {
                const int mk = mrow[(size_t)reg * SS + k0 + nt * 16 + l15];
                sv[nt] = mk ? sacc[nt][reg] * 0.125f : -1.0e9f;
            }
            float mx = fmaxf(fmaxf(sv[0], sv[1]), fmaxf(sv[2], sv[3]));
            mx = fmaxf(mx, __shfl_xor(mx, 1, 16));
            mx = fmaxf(mx, __shfl_xor(mx, 2, 16));
            mx = fmaxf(mx, __shfl_xor(mx, 4, 16));
            mx = fmaxf(mx, __shfl_xor(mx, 8, 16));

            const float m_new = fmaxf(m_run[reg], mx);
            const float alpha = __expf(m_run[reg] - m_new);
            float rs = 0.f;
            #pragma unroll
            for (int nt = 0; nt < 4; nt++) {
                p[reg][nt] = __expf(sv[nt] - m_new);
                rs += p[reg][nt];
            }
            rs += __shfl_xor(rs, 1, 16);
            rs += __shfl_xor(rs, 2, 16);
            rs += __shfl_xor(rs, 4, 16);
            rs += __shfl_xor(rs, 8, 16);

            l_run[reg] = l_run[reg] * alpha + rs;
            m_run[reg] = m_new;
            #pragma unroll
            for (int dt = 0; dt < 4; dt++) oacc[dt][reg] *= alpha;
        }

        #pragma unroll
        for (int reg = 0; reg < 4; reg++) {
            #pragma unroll
            for (int nt = 0; nt < 4; nt++) {
                const float mine  = p[reg][nt];
                const float other = __shfl_xor(mine, 1, 16);
                if ((lane & 1) == 0)
                    Ps[w][quad * 4 + reg][nt * 8 + (l15 >> 1)] = pack2(mine, other);
            }
        }
        __syncthreads();

        #pragma unroll
        for (int kt = 0; kt < 2; kt++) {
            union { uint4 u; s8 s; } pf;
            pf.u = *(const uint4*)&Ps[w][l15][kt * 16 + quad * 4];
            #pragma unroll
            for (int dt = 0; dt < 4; dt++) {
                union { uint4 u; s8 s; } vf;
                vf.u = *(const uint4*)&Vs[dt * 16 + l15][kt * 16 + quad * 4];
                oacc[dt] = MFMA(pf.s, vf.s, oacc[dt]);
            }
        }
    }

    #pragma unroll
    for (int reg = 0; reg < 4; reg++) {
        const float inv = 1.0f / l_run[reg];
        #pragma unroll
        for (int dt = 0; dt < 4; dt++) {
            O[base + (size_t)(q0 + w * 16 + quad * 4 + reg) * DMODEL + dt * 16 + l15] =
                f2bf(oacc[dt][reg] * inv);
        }
    }
}

// ---------------------------------------------------------------------------
extern "C" void kernel_launch(void* const* d_in, const int* in_sizes, int n_in,
                              void* d_out, int out_size, void* d_ws, size_t ws_size,
                              hipStream_t stream)
{
    const float* q    = (const float*)d_in[0];
    const float* k    = (const float*)d_in[1];
    const float* v    = (const float*)d_in[2];
    const int*   mask = (const int*)  d_in[3];
    const float* Wq   = (const float*)d_in[4];
    const float* bq   = (const float*)d_in[5];
    const float* Wk   = (const float*)d_in[6];
    const float* bk   = (const float*)d_in[7];
    const float* Wv   = (const float*)d_in[8];
    const float* bv   = (const float*)d_in[9];
    const float* Wo   = (const float*)d_in[10];
    const float* bo   = (const float*)d_in[11];
    float* out = (float*)d_out;

    // ws: 4 bf16 planes [4096x768] (25.2 MB) + 4 bf16 weight mats (4.5 MB)
    bf16_t* wsb = (bf16_t*)d_ws;
    const size_t plane = (size_t)MROWS * DMODEL;   // 3,145,728
    bf16_t* Qp  = wsb;
    bf16_t* Kp  = wsb + plane;
    bf16_t* Vp  = wsb + 2 * plane;
    bf16_t* Ctx = wsb + 3 * plane;
    bf16_t* Wqb = wsb + 4 * plane;
    bf16_t* Wkb = Wqb + WELEM;
    bf16_t* Wvb = Wkb + WELEM;
    bf16_t* Wob = Wvb + WELEM;

    cvt_weights<<<dim3(WELEM / 1024, 4), 256, 0, stream>>>(Wq, Wk, Wv, Wo, Wqb);

    // fused Q/K/V projections: grid (6, 32, 3)
    gemm_tiled<float, bf16_t><<<dim3(DMODEL / 128, MROWS / 128, 3), 256, 0, stream>>>(
        q, k, v, Wqb, Wkb, Wvb, bq, bk, bv, Qp, Kp, Vp);

    attn_mfma<<<dim3(SS / 64, NHEAD, BB), 256, 0, stream>>>(Qp, Kp, Vp, mask, Ctx);

    // output projection: grid (6, 32, 1)
    gemm_tiled<bf16_t, float><<<dim3(DMODEL / 128, MROWS / 128, 1), 256, 0, stream>>>(
        Ctx, Ctx, Ctx, Wob, Wob, Wob, bo, bo, bo, out, out, out);
}